// Round 15
// baseline (178.729 us; speedup 1.0000x reference)
//
#include <hip/hip_runtime.h>
#include <math.h>

#define QMAXF 127.0f
#define EPSF  1e-8f
#define CIN   256
#define COUT  128
#define HW    3136        // 56*56
#define W_    56
#define NPOOL 3211264     // 32*128*28*28

typedef unsigned short u16;
typedef unsigned int   u32;
typedef unsigned char  u8;
typedef __attribute__((ext_vector_type(4))) int i32x4;

// ws float-index layout
#define WQ_OFF   8        // wqd[256] (f32)
#define BF_OFF   264      // b_fold[256]
#define EMAX_OFF 520      // per-channel enc(max) u32[256]
#define EMIN_OFF 776      // per-channel enc(min) u32[256]
#define CS_OFF   1032     // conv_s[128]
#define CSS2_OFF 1160     // s2*conv_s[128]
#define CWB_OFF  1288     // qcw as i8 [128][256] = 8192 float slots
#define A8_OFF   9480     // a-u8 [32][256][3136] = 25.7 MB (6422528 float slots)
// total ~25.8 MB

__device__ __forceinline__ float qclip(float v) {
    return fminf(fmaxf(v, -128.0f), 127.0f);
}
__device__ __forceinline__ u32 encf(float f) {
    u32 u = __float_as_uint(f);
    return (u & 0x80000000u) ? ~u : (u | 0x80000000u);
}
__device__ __forceinline__ float decf(u32 k) {
    return __uint_as_float((k & 0x80000000u) ? (k ^ 0x80000000u) : ~k);
}

__device__ __forceinline__ void block_max_atomic(float v, float* red, u32* dst) {
    #pragma unroll
    for (int off = 32; off > 0; off >>= 1) v = fmaxf(v, __shfl_xor(v, off));
    const int lane = threadIdx.x & 63, wid = threadIdx.x >> 6;
    if (lane == 0) red[wid] = v;
    __syncthreads();
    if (threadIdx.x == 0) {
        const int nw = blockDim.x >> 6;
        float m = red[0];
        for (int i = 1; i < nw; ++i) m = fmaxf(m, red[i]);
        atomicMax(dst, __float_as_uint(m));
    }
}

// K0w: per-row quant of conv_w -> i8 + conv_s; extra block inits enc arrays
__global__ void k0w(const float* __restrict__ cw, float* __restrict__ ws) {
    const int t = threadIdx.x;
    if (blockIdx.x == COUT) {
        ((u32*)ws)[EMAX_OFF + t] = 0u;
        ((u32*)ws)[EMIN_OFF + t] = 0xFFFFFFFFu;
        if (t < 2) ((u32*)ws)[2 + t] = 0u;   // y-max, pool-max atomics
        return;
    }
    __shared__ float red[4];
    const int o = blockIdx.x;
    const float wv = cw[o * CIN + t];
    float v = fabsf(wv);
    #pragma unroll
    for (int off = 32; off > 0; off >>= 1) v = fmaxf(v, __shfl_xor(v, off));
    if ((t & 63) == 0) red[t >> 6] = v;
    __syncthreads();
    const float mx = fmaxf(fmaxf(red[0], red[1]), fmaxf(red[2], red[3]));
    const float s = fmaxf(mx / QMAXF, EPSF);
    const float q = qclip(rintf(wv / s));
    ((signed char*)(ws + CWB_OFF))[o * CIN + t] = (signed char)(int)q;
    if (t == 0) ws[CS_OFF + o] = s;
}

// K1: per-(b,c)-row min/max of x -> per-channel enc atomics
__global__ void k1_minmax(const float* __restrict__ x, float* __restrict__ ws) {
    __shared__ float red[8];
    const int row = blockIdx.x;                       // 32*256 rows
    const float4* xr = (const float4*)(x + (size_t)row * HW);
    float mx = -3.402823466e38f, mn = 3.402823466e38f;
    for (int i = threadIdx.x; i < HW / 4; i += 256) {
        const float4 v = xr[i];
        mx = fmaxf(mx, fmaxf(fmaxf(v.x, v.y), fmaxf(v.z, v.w)));
        mn = fminf(mn, fminf(fminf(v.x, v.y), fminf(v.z, v.w)));
    }
    #pragma unroll
    for (int off = 32; off > 0; off >>= 1) {
        mx = fmaxf(mx, __shfl_xor(mx, off));
        mn = fminf(mn, __shfl_xor(mn, off));
    }
    if ((threadIdx.x & 63) == 0) {
        red[threadIdx.x >> 6] = mx;
        red[4 + (threadIdx.x >> 6)] = mn;
    }
    __syncthreads();
    if (threadIdx.x == 0) {
        mx = fmaxf(fmaxf(red[0], red[1]), fmaxf(red[2], red[3]));
        mn = fminf(fminf(red[4], red[5]), fminf(red[6], red[7]));
        const int c = row & (CIN - 1);
        atomicMax((u32*)ws + EMAX_OFF + c, encf(mx));
        atomicMin((u32*)ws + EMIN_OFF + c, encf(mn));
    }
}

// K0b: s1 from channel extremes; BN fold + quant; s2 from per-channel affine
// endpoints; CSS2[o] = s2*conv_s[o].
__global__ void k0b(const float* __restrict__ g, const float* __restrict__ be,
                    const float* __restrict__ mnp, const float* __restrict__ vr,
                    float* __restrict__ ws) {
    __shared__ float red[4];
    __shared__ float s1sh, s2sh;
    const int t = threadIdx.x;
    const float cmax = decf(((u32*)ws)[EMAX_OFF + t]);
    const float cmin = decf(((u32*)ws)[EMIN_OFF + t]);
    float v = fmaxf(fabsf(cmax), fabsf(cmin));
    #pragma unroll
    for (int off = 32; off > 0; off >>= 1) v = fmaxf(v, __shfl_xor(v, off));
    if ((t & 63) == 0) red[t >> 6] = v;
    __syncthreads();
    if (t == 0) {
        const float m1 = fmaxf(fmaxf(red[0], red[1]), fmaxf(red[2], red[3]));
        ws[0] = m1;
        s1sh = fmaxf(m1 / QMAXF, EPSF);
    }
    __syncthreads();
    const float s1 = s1sh;
    const float wf = g[t] / sqrtf(vr[t] + 1e-5f);
    const float bf = be[t] - mnp[t] * wf;
    const float sw = fmaxf(fabsf(wf) / QMAXF, EPSF);
    const float q  = qclip(rintf(wf / sw));
    const float wqd = __fmul_rn(q, sw);
    ws[WQ_OFF + t] = wqd;
    ws[BF_OFF + t] = bf;
    const float q1h = qclip(rintf(cmax / s1));
    const float q1l = qclip(rintf(cmin / s1));
    const float xh = __fadd_rn(__fmul_rn(__fmul_rn(q1h, s1), wqd), bf);
    const float xl = __fadd_rn(__fmul_rn(__fmul_rn(q1l, s1), wqd), bf);
    float m2 = fmaxf(fabsf(xh), fabsf(xl));
    __syncthreads();
    #pragma unroll
    for (int off = 32; off > 0; off >>= 1) m2 = fmaxf(m2, __shfl_xor(m2, off));
    if ((t & 63) == 0) red[t >> 6] = m2;
    __syncthreads();
    if (t == 0) {
        const float m2f = fmaxf(fmaxf(red[0], red[1]), fmaxf(red[2], red[3]));
        ws[1] = m2f;
        s2sh = fmaxf(m2f / QMAXF, EPSF);
    }
    __syncthreads();
    if (t < COUT) ws[CSS2_OFF + t] = __fmul_rn(s2sh, ws[CS_OFF + t]);
}

// K2: streaming transform x -> a-u8 (exact reference op chain, coalesced rows)
__global__ __launch_bounds__(256) void k2_xform(const float* __restrict__ x,
                                                float* __restrict__ ws) {
    const int row = blockIdx.x;                 // (b,c) row, 8192 total
    const int c   = row & (CIN - 1);
    const float s1 = fmaxf(ws[0] / QMAXF, EPSF);
    const float s2 = fmaxf(ws[1] / QMAXF, EPSF);
    const float wqd = ws[WQ_OFF + c];
    const float bf  = ws[BF_OFF + c];
    const float4* xr = (const float4*)(x + (size_t)row * HW);
    uchar4* ar = (uchar4*)((u8*)(ws + A8_OFF) + (size_t)row * HW);
    for (int i = threadIdx.x; i < HW / 4; i += 256) {
        const float4 v = xr[i];
        const float vv[4] = {v.x, v.y, v.z, v.w};
        u32 pk = 0;
        #pragma unroll
        for (int u = 0; u < 4; ++u) {
            const float q1 = qclip(rintf(vv[u] / s1));
            const float xd = __fmul_rn(q1, s1);
            const float x2 = __fadd_rn(__fmul_rn(xd, wqd), bf);
            const float q2 = qclip(rintf(x2 / s2));
            const float a  = fmaxf(q2, 0.0f);
            pk |= ((u32)(int)a) << (8 * u);
        }
        *(u32*)&ar[i] = pk;
    }
}

// K3 core: i8 GEMM on one (b, row-pair rp, col-chunk c0) tile.
// POOL=0: y-max only -> ws[2].  POOL=1: fused integer pool -> out, max -> ws[3].
template<int POOL>
__global__ __launch_bounds__(256) void k3_core(float* __restrict__ ws,
                                               float* __restrict__ out) {
    __shared__ __align__(16) u8 Xs[32 * 256];   // 8 KB [pixel-slot][k swizzled]
    __shared__ float Css2s[COUT];
    __shared__ float red[4];

    const int t  = threadIdx.x;
    const int l  = t & 63, w = t >> 6;
    const int wc = w * 32;                      // wave cout base
    const int lm = l & 15, lh = l >> 4;

    const int tile = blockIdx.x;                // 32 b x 28 rp x 4 chunks
    const int b    = tile / 112;
    const int r112 = tile % 112;
    const int rp   = r112 >> 2;
    const int ci   = r112 & 3;
    const int c0   = (ci < 3) ? ci * 16 : 40;   // chunk 3 overlaps chunk 2 (benign)

    const u8* A8 = (const u8*)(ws + A8_OFF);
    const signed char* cwb8 = (const signed char*)(ws + CWB_OFF);
    if (t < COUT) Css2s[t] = ws[CSS2_OFF + t];

    // ---- stage tile: 8 uchar4 loads/thread, byte-transpose into swizzled Xs
    {
        const int c8 = t >> 3, q = t & 7;
        const int p0 = (q >> 2) * 16 + (q & 3) * 4;       // pixel-slot base
        const size_t rowoff = (size_t)(2 * rp + (q >> 2)) * W_ + c0 + (q & 3) * 4;
        const u8* basep = A8 + (size_t)b * CIN * HW + rowoff;
        #pragma unroll
        for (int j = 0; j < 8; ++j) {
            const int c = c8 + 32 * j;
            const u32 v = *(const u32*)(basep + (size_t)c * HW);
            const int gr = (c >> 4), cl = c & 15;
            #pragma unroll
            for (int u = 0; u < 4; ++u) {
                const int p = p0 + u;
                Xs[p * 256 + (((gr + p + (p >> 3)) & 15) * 16) + cl] =
                    (u8)((v >> (8 * u)) & 0xFFu);
            }
        }
    }
    __syncthreads();

    // ---- i8 MFMA loop (r13-validated fragments); W from global (L2-hot) ----
    i32x4 acc[2][2];
    #pragma unroll
    for (int m = 0; m < 2; ++m)
        #pragma unroll
        for (int n = 0; n < 2; ++n) acc[m][n] = (i32x4)0;

    const signed char* wb0 = cwb8 + (wc + lm) * CIN + lh * 16;
    const signed char* wb1 = cwb8 + (wc + 16 + lm) * CIN + lh * 16;

    #pragma unroll
    for (int it = 0; it < 4; ++it) {
        const int slot = it * 4 + lh;
        i32x4 xf[2], wfr[2];
        #pragma unroll
        for (int n = 0; n < 2; ++n) {
            const int pp = n * 16 + lm;
            xf[n] = *(const i32x4*)&Xs[pp * 256 + (((slot + pp + (pp >> 3)) & 15) * 16)];
        }
        wfr[0] = *(const i32x4*)(wb0 + it * 64);
        wfr[1] = *(const i32x4*)(wb1 + it * 64);
        #pragma unroll
        for (int m = 0; m < 2; ++m)
            #pragma unroll
            for (int n = 0; n < 2; ++n)
                acc[m][n] = __builtin_amdgcn_mfma_i32_16x16x64_i8(
                                wfr[m], xf[n], acc[m][n], 0, 0, 0);
    }

    float mloc = 0.0f;
    if (POOL == 0) {
        // ---- y-max only ----
        #pragma unroll
        for (int m = 0; m < 2; ++m)
            #pragma unroll
            for (int n = 0; n < 2; ++n)
                #pragma unroll
                for (int r = 0; r < 4; ++r) {
                    const int o = wc + m * 16 + lh * 4 + r;
                    mloc = fmaxf(mloc, fabsf(__fmul_rn((float)acc[m][n][r], Css2s[o])));
                }
        block_max_atomic(mloc, red, (u32*)ws + 2);
    } else {
        // ---- fused integer-domain 2x2 pool; write pooled to out ----
        const float s3 = fmaxf(ws[2] / QMAXF, EPSF);
        #pragma unroll
        for (int m = 0; m < 2; ++m) {
            #pragma unroll
            for (int r = 0; r < 4; ++r) {
                const int o = wc + m * 16 + lh * 4 + r;
                const float cs = Css2s[o];
                // q3 per row (n=0: row 2rp, n=1: row 2rp+1), same col lane
                const float y0 = __fmul_rn((float)acc[m][0][r], cs);
                const float y1 = __fmul_rn((float)acc[m][1][r], cs);
                const float q30 = qclip(rintf(y0 / s3));
                const float q31 = qclip(rintf(y1 / s3));
                const float fsum = q30 + q31;                 // exact (small ints)
                const float cross = __shfl_xor(fsum, 1);      // col-pair partner
                if ((lm & 1) == 0) {
                    const float total = fsum + cross;          // exact
                    const float pooled = __fmul_rn(__fmul_rn(total, 0.25f), s3);
                    out[((size_t)(b * COUT + o) * 28 + rp) * 28 + (c0 >> 1) + (lm >> 1)]
                        = pooled;
                    mloc = fmaxf(mloc, fabsf(pooled));
                }
            }
        }
        block_max_atomic(mloc, red, (u32*)ws + 3);
    }
}

// K5: final fake-quant in place (float4 grid-stride) + write act_s scalar
__global__ void k5_final(float* __restrict__ out, const float* __restrict__ ws) {
    const float s4 = fmaxf(ws[3] / QMAXF, EPSF);
    const int n4 = NPOOL / 4;
    for (int i = blockIdx.x * 256 + threadIdx.x; i < n4; i += 3136 * 256) {
        float4 v = *(float4*)(out + 4 * (size_t)i);
        v.x = __fmul_rn(qclip(rintf(v.x / s4)), s4);
        v.y = __fmul_rn(qclip(rintf(v.y / s4)), s4);
        v.z = __fmul_rn(qclip(rintf(v.z / s4)), s4);
        v.w = __fmul_rn(qclip(rintf(v.w / s4)), s4);
        *(float4*)(out + 4 * (size_t)i) = v;
    }
    if (blockIdx.x == 0 && threadIdx.x == 0) out[NPOOL] = s4;
}

extern "C" void kernel_launch(void* const* d_in, const int* in_sizes, int n_in,
                              void* d_out, int out_size, void* d_ws, size_t ws_size,
                              hipStream_t stream) {
    const float* x     = (const float*)d_in[0];
    const float* gamma = (const float*)d_in[1];
    const float* beta  = (const float*)d_in[2];
    const float* mean  = (const float*)d_in[3];
    const float* var   = (const float*)d_in[4];
    const float* cw    = (const float*)d_in[5];
    float* out = (float*)d_out;
    float* ws  = (float*)d_ws;

    hipLaunchKernelGGL(k0w, dim3(COUT + 1), dim3(256), 0, stream, cw, ws);
    hipLaunchKernelGGL(k1_minmax, dim3(32 * CIN), dim3(256), 0, stream, x, ws);
    hipLaunchKernelGGL(k0b, dim3(1), dim3(256), 0, stream, gamma, beta, mean, var, ws);
    hipLaunchKernelGGL(k2_xform, dim3(32 * CIN), dim3(256), 0, stream, x, ws);
    hipLaunchKernelGGL((k3_core<0>), dim3(3584), dim3(256), 0, stream, ws, out);
    hipLaunchKernelGGL((k3_core<1>), dim3(3584), dim3(256), 0, stream, ws, out);
    hipLaunchKernelGGL(k5_final, dim3(3136), dim3(256), 0, stream, out, ws);
}